// Round 14
// baseline (268.975 us; speedup 1.0000x reference)
//
#include <hip/hip_runtime.h>
#include <hip/hip_bf16.h>

// Problem constants (fixed-size problem)
constexpr int H      = 4;
constexpr int D_SUB  = 32;
constexpr int D_HID  = 128;
constexpr int B      = 100;
constexpr int N_PER  = 5000;
constexpr int N      = B * N_PER;        // 500000
constexpr int DEG    = 16;
constexpr int E      = N * DEG;          // 8000000
constexpr int E_PER  = N_PER * DEG;      // 80000
constexpr int K_PER  = 2500;
constexpr int NK     = B * K_PER;        // 250000

constexpr int EPB    = 4096;             // edges per block (compaction)
constexpr int EPT    = 16;               // edges per thread (compaction)
constexpr int NBLK_E = (E + EPB - 1) / EPB; // 1954

constexpr int SUBR   = 1250;             // nodes per fused-score block (4 blocks/graph)
constexpr int LCAP   = 22250;            // list capacity: mean 20000 + skew 1250 + 8 sigma
constexpr int NEPOCH = 8;                // P3 epochs (appends ordered across epochs)
constexpr int EP_I4  = (E_PER / 4) / NEPOCH;  // 2500 int4 per epoch

constexpr int M      = 8192;             // bitonic size (pow2 >= N_PER)

// decoupled-lookback status flags
constexpr unsigned long long FLG_A = 1ull << 62;   // aggregate ready
constexpr unsigned long long FLG_I = 2ull << 62;   // inclusive ready

// bijective XCD-chunked block swizzle: grid must be a multiple of 8
__device__ __forceinline__ int swz8(int bid, int chunk) {
    return (bid & 7) * chunk + (bid >> 3);
}

// padded LDS index for u64 keys: +1 slot per 8 -> breaks 64B-stride bank aliasing
__device__ __forceinline__ int ph(int i) { return i + (i >> 3); }

// ---------------- in-degree count: per-graph-half LDS histogram, plain stores ----------------
__global__ __launch_bounds__(1024) void k_count(const int* __restrict__ col,
                                                int* __restrict__ cnt2) {
    __shared__ int h[N_PER];  // 20 KB
    int lb = swz8(blockIdx.x, 25);       // 0..199, XCD-contiguous graphs
    int g = lb >> 1, half = lb & 1;
    for (int i = threadIdx.x; i < N_PER; i += 1024) h[i] = 0;
    __syncthreads();
    int ebase = g * E_PER + half * (E_PER / 2);
    int nbase = g * N_PER;
    const int4* c4 = (const int4*)(col + ebase);    // 16B-aligned
    for (int i = threadIdx.x; i < E_PER / 2 / 4; i += 1024) {
        int4 v = c4[i];
        atomicAdd(&h[v.x - nbase], 1);
        atomicAdd(&h[v.y - nbase], 1);
        atomicAdd(&h[v.z - nbase], 1);
        atomicAdd(&h[v.w - nbase], 1);
    }
    __syncthreads();
    int* dst = cnt2 + half * N + nbase;
    for (int i = threadIdx.x; i < N_PER; i += 1024) dst[i] = h[i];
}

// ---------------- deg = halves sum; dis = (1+deg)^-0.5 (int4/float4 vectorized) ----------------
__global__ void k_dis(const int4* __restrict__ cnt2a, const int4* __restrict__ cnt2b,
                      int4* __restrict__ cnt, float4* __restrict__ dis) {
    int i = blockIdx.x * blockDim.x + threadIdx.x;
    if (i < N / 4) {
        int4 a = cnt2a[i], b = cnt2b[i];
        int4 c = make_int4(a.x + b.x, a.y + b.y, a.z + b.z, a.w + b.w);
        cnt[i] = c;
        float4 d;
        d.x = __fdiv_rn(1.0f, __fsqrt_rn((float)(1 + c.x)));
        d.y = __fdiv_rn(1.0f, __fsqrt_rn((float)(1 + c.y)));
        d.z = __fdiv_rn(1.0f, __fsqrt_rn((float)(1 + c.z)));
        d.w = __fdiv_rn(1.0f, __fsqrt_rn((float)(1 + c.w)));
        dis[i] = d;
    }
}

// ---------------- fused: adjacency-in-LDS + bit-exact score ----------------
// 4 blocks per graph (SUBR=1250): per-block edge-scan work is constant regardless of
// subrange size, so halving the block count halves chip-level scan work (the dominant
// issue-bound cost). 119 KB LDS -> 1 block/CU.
__global__ __launch_bounds__(1024) void k_score_fused(const int* __restrict__ row,
                                                      const int* __restrict__ col,
                                                      const int* __restrict__ cnt,
                                                      const float* __restrict__ dis,
                                                      const float* __restrict__ scW,
                                                      const float* __restrict__ scB,
                                                      float* __restrict__ score) {
    __shared__ float dis_l[N_PER];   // 20000 B
    __shared__ int   wsum[16];       //    64 B
    __shared__ int   offs_l[SUBR];   //  5000 B
    __shared__ int   curs_l[SUBR];   //  5000 B
    __shared__ int   list[LCAP];     // 89000 B   total ~119.1 KB -> 1 block/CU
    int lb = swz8(blockIdx.x, 50);   // 0..399, XCD-contiguous (4 blocks of a graph share an XCD)
    int g = lb >> 2, q = lb & 3;
    int t = threadIdx.x;
    int nbase = g * N_PER;
    int ebase = g * E_PER;
    int lo = q * SUBR;

    // P1: load precomputed dis for the whole graph into LDS (float4, L2-hot)
    const float4* d4 = (const float4*)(dis + nbase);   // 20000 B offset -> 16B aligned
    for (int j4 = t; j4 < N_PER / 4; j4 += 1024) {
        float4 dv4 = d4[j4];
        int j = 4 * j4;
        dis_l[j]     = dv4.x;
        dis_l[j + 1] = dv4.y;
        dis_l[j + 2] = dv4.z;
        dis_l[j + 3] = dv4.w;
    }

    // P2: scan of 1250 degrees, 2 nodes per thread (t < 625), wave-shuffle over pair sums
    int va = 0, vb = 0;
    if (t < SUBR / 2) {
        va = cnt[nbase + lo + 2 * t];
        vb = cnt[nbase + lo + 2 * t + 1];
    }
    int pair = va + vb;
    int lane = t & 63, wid = t >> 6;
    int x = pair;
#pragma unroll
    for (int s = 1; s < 64; s <<= 1) {
        int o = __shfl_up(x, s, 64);
        if (lane >= s) x += o;
    }
    if (lane == 63) wsum[wid] = x;
    __syncthreads();
    if (wid == 0) {
        int ws = (lane < 16) ? wsum[lane] : 0;
#pragma unroll
        for (int s = 1; s < 16; s <<= 1) {
            int o = __shfl_up(ws, s, 64);
            if (lane >= s) ws += o;
        }
        if (lane < 16) wsum[lane] = ws;
    }
    __syncthreads();
    if (t < SUBR / 2) {
        int incl = x + (wid > 0 ? wsum[wid - 1] : 0);
        int excl = incl - pair;
        offs_l[2 * t]     = excl + 2 * t;             // +n bank skew
        offs_l[2 * t + 1] = excl + va + 2 * t + 1;
        curs_l[2 * t] = 0;
        curs_l[2 * t + 1] = 0;
    }
    __syncthreads();

    // P3: stream edges in epochs (int4 col AND row); append matches,
    // packed (e_local<<13)|row_local. Barrier per epoch orders appends across epochs.
    const int4* c4 = (const int4*)(col + ebase);    // 16B-aligned
    const int4* r4 = (const int4*)(row + ebase);
    for (int ep = 0; ep < NEPOCH; ep++) {
        for (int i4 = ep * EP_I4 + t; i4 < (ep + 1) * EP_I4; i4 += 1024) {
            int4 cv = c4[i4];
            int4 rv = r4[i4];
            int i0 = 4 * i4;
#pragma unroll
            for (int m = 0; m < 4; m++) {
                int cl = ((m == 0) ? cv.x : (m == 1) ? cv.y : (m == 2) ? cv.z : cv.w) - nbase;
                int rl = ((m == 0) ? rv.x : (m == 1) ? rv.y : (m == 2) ? rv.z : rv.w) - nbase;
                unsigned d = (unsigned)(cl - lo);
                if (d < (unsigned)SUBR) {
                    int i = i0 + m;
                    int slot = atomicAdd(&curs_l[d], 1);
                    int pos = offs_l[d] + slot;
                    if (pos < LCAP) list[pos] = (i << 13) | rl;
                }
            }
        }
        __syncthreads();
    }

    // P4: insertion sort ascending edge id + bit-exact fold; 2 passes (1250 nodes)
    float w  = scW[0];
    float sb = scB[0];
    for (int n = t; n < SUBR; n += 1024) {
        int base = offs_l[n];
        int k = curs_l[n];                   // appended count == in-degree
        if (base + k > LCAP) k = 0;          // overflow guard (probability ~0)
        for (int i = 1; i < k; i++) {
            int key = list[base + i];
            int j = i - 1;
            while (j >= 0 && list[base + j] > key) { list[base + j + 1] = list[base + j]; j--; }
            list[base + j + 1] = key;
        }
        float dv = dis_l[lo + n];
        float s = 0.0f;
        for (int i = 0; i < k; i++) {
            int rl = list[base + i] & 8191;
            s = __fadd_rn(s, __fmul_rn(w, __fmul_rn(dis_l[rl], dv)));
        }
        s = __fadd_rn(s, __fmul_rn(w, __fmul_rn(dv, dv)));  // self-loop term
        s = __fadd_rn(s, sb);
        score[nbase + lo + n] = s;
    }
}

// ---------------- per-graph stable top-k: register-blocked bitonic sort ----------------
__global__ __launch_bounds__(1024) void k_topk(const float* __restrict__ score,
                                               float* __restrict__ out_batch,
                                               float* __restrict__ out_perm,
                                               int* __restrict__ perm_i,
                                               int* __restrict__ n_idx) {
    __shared__ unsigned long long keys[M + (M >> 3)];  // 9216 u64 = 73728 B (padded)
    int b = blockIdx.x, t = threadIdx.x;
    int base = 8 * t;

    unsigned long long v[8];
    if (t < 625) {   // 8*625 = 5000 = N_PER exactly
        const float4* s4 = (const float4*)(score + b * N_PER + base);
        float4 f0 = s4[0], f1 = s4[1];
        float fs[8] = {f0.x, f0.y, f0.z, f0.w, f1.x, f1.y, f1.z, f1.w};
#pragma unroll
        for (int m = 0; m < 8; m++) {
            unsigned u = __float_as_uint(fs[m]);
            unsigned asc = u ^ ((u & 0x80000000u) ? 0xFFFFFFFFu : 0x80000000u);
            v[m] = ((unsigned long long)(~asc) << 32) | (unsigned)(base + m);
        }
    } else {
#pragma unroll
        for (int m = 0; m < 8; m++) v[m] = ~0ull;  // padding sorts last
    }

#define CEV(x, y, up) { if ((v[x] > v[y]) == (up)) { unsigned long long tmp = v[x]; v[x] = v[y]; v[y] = tmp; } }
    CEV(0, 1, true)  CEV(2, 3, false) CEV(4, 5, true)  CEV(6, 7, false)      // k=2
    CEV(0, 2, true)  CEV(1, 3, true)  CEV(4, 6, false) CEV(5, 7, false)      // k=4 j=2
    CEV(0, 1, true)  CEV(2, 3, true)  CEV(4, 5, false) CEV(6, 7, false)      // k=4 j=1
    {
        bool u8 = ((t & 1) == 0);                                            // k=8
        CEV(0, 4, u8) CEV(1, 5, u8) CEV(2, 6, u8) CEV(3, 7, u8)
        CEV(0, 2, u8) CEV(1, 3, u8) CEV(4, 6, u8) CEV(5, 7, u8)
        CEV(0, 1, u8) CEV(2, 3, u8) CEV(4, 5, u8) CEV(6, 7, u8)
    }
#pragma unroll
    for (int m = 0; m < 8; m++) keys[ph(base + m)] = v[m];
    __syncthreads();

    for (int k = 16; k <= M; k <<= 1) {
        bool last = (k == M);
        for (int j = k >> 1; j >= 8; j >>= 1) {
            int np = (last && j < (M >> 1)) ? (M >> 2) : (M >> 1);
            for (int p = t; p < np; p += 1024) {
                int i = ((p & ~(j - 1)) << 1) | (p & (j - 1));
                int ip = i | j;
                bool up = ((i & k) == 0);
                unsigned long long a = keys[ph(i)];
                unsigned long long c = keys[ph(ip)];
                if ((a > c) == up) { keys[ph(i)] = c; keys[ph(ip)] = a; }
            }
            __syncthreads();
        }
        int nb = last ? 512 : 1024;   // last stage: register pass only on [0,4096)
        if (t < nb) {
            bool up = ((base & k) == 0);
            unsigned long long w[8];
#pragma unroll
            for (int m = 0; m < 8; m++) w[m] = keys[ph(base + m)];
#define CEW(x, y) { if ((w[x] > w[y]) == up) { unsigned long long tmp = w[x]; w[x] = w[y]; w[y] = tmp; } }
            CEW(0, 4) CEW(1, 5) CEW(2, 6) CEW(3, 7)   // j=4
            CEW(0, 2) CEW(1, 3) CEW(4, 6) CEW(5, 7)   // j=2
            CEW(0, 1) CEW(2, 3) CEW(4, 5) CEW(6, 7)   // j=1
#pragma unroll
            for (int m = 0; m < 8; m++) keys[ph(base + m)] = w[m];
        }
        __syncthreads();
    }

    for (int r = t; r < K_PER; r += 1024) {
        unsigned long long key = keys[ph(r)];
        int idx = (int)(key & 0xFFFFFFFFull);
        int gl = b * N_PER + idx;
        int ni = b * K_PER + r;
        perm_i[ni] = gl;
        n_idx[gl] = ni;
        out_perm[ni] = (float)gl;
        out_batch[ni] = (float)b;
    }
}

// ---------------- x_new = x[perm] * tanh(score[perm]) ----------------
__global__ void k_xnew(const float4* __restrict__ x4, const float* __restrict__ score,
                       const int* __restrict__ perm_i, float4* __restrict__ out4) {
    int tid = blockIdx.x * blockDim.x + threadIdx.x;
    if (tid >= NK * (D_HID / 4)) return;
    int i = tid >> 5;       // row (D_HID/4 = 32 float4 per row)
    int c = tid & 31;
    int g = perm_i[i];
    float ts = tanhf(score[g]);
    float4 v = x4[(long)g * 32 + c];
    v.x *= ts; v.y *= ts; v.z *= ts; v.w *= ts;
    out4[tid] = v;
}

// ---------------- prefill: n_idx = -1, status = 0 (edge tail handled by k_filltail) ----------------
__global__ void k_prefill(int4* __restrict__ n_idx4,
                          unsigned long long* __restrict__ status) {
    int i = blockIdx.x * blockDim.x + threadIdx.x;
    int stride = gridDim.x * blockDim.x;
    int4 mi = make_int4(-1, -1, -1, -1);
    for (int j = i; j < N / 4; j += stride) n_idx4[j] = mi;
    for (int j = i; j < NBLK_E; j += stride) status[j] = 0ull;
}

// ---------------- single-pass order-preserving edge compaction (decoupled lookback) ----------------
__global__ __launch_bounds__(256) void k_compact(const int* __restrict__ row,
                                                 const int* __restrict__ col,
                                                 const int* __restrict__ n_idx,
                                                 unsigned long long* __restrict__ status,
                                                 float* __restrict__ oe0,
                                                 float* __restrict__ oe1) {
    __shared__ int wsum[4];
    __shared__ int excl_sh;
    int blk = blockIdx.x, t = threadIdx.x;
    int base = blk * EPB + t * EPT;
    int rr[EPT], cc[EPT];
    int cnt = 0;
    if (blk < NBLK_E - 1) {
        // full block: int4 fast path (base is 16-int aligned)
#pragma unroll
        for (int i4 = 0; i4 < 4; i4++) {
            int4 rv = ((const int4*)(row + base))[i4];
            int4 cv = ((const int4*)(col + base))[i4];
            rr[4 * i4 + 0] = n_idx[rv.x];  cc[4 * i4 + 0] = n_idx[cv.x];
            rr[4 * i4 + 1] = n_idx[rv.y];  cc[4 * i4 + 1] = n_idx[cv.y];
            rr[4 * i4 + 2] = n_idx[rv.z];  cc[4 * i4 + 2] = n_idx[cv.z];
            rr[4 * i4 + 3] = n_idx[rv.w];  cc[4 * i4 + 3] = n_idx[cv.w];
        }
#pragma unroll
        for (int i = 0; i < EPT; i++)
            if (rr[i] >= 0 && cc[i] >= 0) cnt++;
    } else {
        // ragged last block: scalar guarded path
#pragma unroll
        for (int i = 0; i < EPT; i++) {
            int e = base + i;
            int rv = -1, cv = -1;
            if (e < E) { rv = n_idx[row[e]]; cv = n_idx[col[e]]; }
            rr[i] = rv; cc[i] = cv;
            if (rv >= 0 && cv >= 0) cnt++;
        }
    }
    // wave-shuffle inclusive scan over 256 threads (4 waves, 2 barriers)
    int lane = t & 63, wid = t >> 6;
    int x = cnt;
#pragma unroll
    for (int s = 1; s < 64; s <<= 1) {
        int o = __shfl_up(x, s, 64);
        if (lane >= s) x += o;
    }
    if (lane == 63) wsum[wid] = x;
    __syncthreads();
    if (t == 0) {
        int a0 = wsum[0], a1 = wsum[1], a2 = wsum[2];
        wsum[1] = a0; wsum[2] = a0 + a1; wsum[3] = a0 + a1 + a2;
        wsum[0] = 0;
    }
    __syncthreads();
    int incl = x + wsum[wid];
    int agg;
    {
        __shared__ int agg_sh;
        if (t == 255) agg_sh = incl;   // thread 255 holds block-inclusive total
        __syncthreads();
        agg = agg_sh;
    }
    if (t == 0) {
        if (blk == 0) {
            atomicExch(&status[0], FLG_I | (unsigned long long)(unsigned)agg);
            excl_sh = 0;
        } else {
            atomicExch(&status[blk], FLG_A | (unsigned long long)(unsigned)agg);
            unsigned long long ex = 0;
            for (int i = blk - 1; i >= 0; i--) {
                unsigned long long sv;
                do { sv = atomicAdd(&status[i], 0ull); } while (sv == 0ull);
                ex += (sv & 0xFFFFFFFFull);
                if (sv & FLG_I) break;
            }
            atomicExch(&status[blk], FLG_I | (ex + (unsigned long long)(unsigned)agg));
            excl_sh = (int)ex;
        }
    }
    __syncthreads();
    int pos = excl_sh + incl - cnt;
#pragma unroll
    for (int i = 0; i < EPT; i++) {
        if (rr[i] >= 0 && cc[i] >= 0) {
            oe0[pos] = (float)rr[i];
            oe1[pos] = (float)cc[i];
            pos++;
        }
    }
}

// ---------------- fill tail [total, E) with -1; total from last lookback status ----------------
__global__ void k_filltail(const unsigned long long* __restrict__ status,
                           float* __restrict__ oe0, float* __restrict__ oe1) {
    int cnt = (int)(status[NBLK_E - 1] & 0xFFFFFFFFull);
    int i = blockIdx.x * blockDim.x + threadIdx.x;
    int stride = gridDim.x * blockDim.x;
    for (int j = cnt + i; j < E; j += stride) { oe0[j] = -1.0f; oe1[j] = -1.0f; }
}

extern "C" void kernel_launch(void* const* d_in, const int* in_sizes, int n_in,
                              void* d_out, int out_size, void* d_ws, size_t ws_size,
                              hipStream_t stream) {
    const float* x   = (const float*)d_in[0];
    const float* scW = (const float*)d_in[4];
    const float* scB = (const float*)d_in[5];
    const int*   edge = (const int*)d_in[6];
    const int*   row = edge;
    const int*   col = edge + E;

    // workspace layout: status (u64, 8B-aligned at base) then ints/floats
    unsigned long long* status = (unsigned long long*)d_ws;   // NBLK_E
    int*   ws_i    = (int*)(status + NBLK_E);
    int*   cnt2    = ws_i;                   // 2N (half histograms)
    int*   deg_cnt = ws_i + 2 * N;           // N  (summed)
    float* dis     = (float*)(ws_i + 3 * N); // N
    float* score   = (float*)(ws_i + 4 * N); // N
    int*   n_idx   = ws_i + 5 * N;           // N
    int*   perm_i  = ws_i + 6 * N;           // NK

    // output layout: x_new [NK, D_HID] | edge_new [2, E] | batch_new [NK] | perm [NK]
    float* out_x     = (float*)d_out;
    float* oe0       = out_x + (size_t)NK * D_HID;
    float* oe1       = oe0 + E;
    float* out_batch = oe1 + E;
    float* out_perm  = out_batch + NK;

    k_prefill<<<1024, 256, 0, stream>>>((int4*)n_idx, status);
    k_count<<<200, 1024, 0, stream>>>(col, cnt2);
    k_dis<<<(N / 4 + 255) / 256, 256, 0, stream>>>((const int4*)cnt2, (const int4*)(cnt2 + N),
                                                   (int4*)deg_cnt, (float4*)dis);
    k_score_fused<<<400, 1024, 0, stream>>>(row, col, deg_cnt, dis, scW, scB, score);
    k_topk<<<B, 1024, 0, stream>>>(score, out_batch, out_perm, perm_i, n_idx);
    k_xnew<<<(NK * (D_HID / 4) + 255) / 256, 256, 0, stream>>>((const float4*)x, score, perm_i,
                                                               (float4*)out_x);
    k_compact<<<NBLK_E, 256, 0, stream>>>(row, col, n_idx, status, oe0, oe1);
    k_filltail<<<4096, 256, 0, stream>>>(status, oe0, oe1);
}

// Round 15
// 255.729 us; speedup vs baseline: 1.0518x; 1.0518x over previous
//
#include <hip/hip_runtime.h>
#include <hip/hip_bf16.h>

// Problem constants (fixed-size problem)
constexpr int H      = 4;
constexpr int D_SUB  = 32;
constexpr int D_HID  = 128;
constexpr int B      = 100;
constexpr int N_PER  = 5000;
constexpr int N      = B * N_PER;        // 500000
constexpr int DEG    = 16;
constexpr int E      = N * DEG;          // 8000000
constexpr int E_PER  = N_PER * DEG;      // 80000
constexpr int K_PER  = 2500;
constexpr int NK     = B * K_PER;        // 250000

constexpr int EPB    = 4096;             // edges per block (compaction)
constexpr int EPT    = 16;               // edges per thread (compaction)
constexpr int NBLK_E = (E + EPB - 1) / EPB; // 1954

constexpr int SUBR   = 625;              // nodes per fused-score block (8 blocks/graph)
constexpr int LCAP   = 11640;            // LDS edge-list capacity (mean 10000 + skew 625 + slack)
constexpr int NEPOCH = 8;                // P3 epochs: appends ordered across epochs ->
                                         // insertion sort sees near-sorted input
constexpr int EP_I4  = (E_PER / 4) / NEPOCH;  // 2500 int4 per epoch

constexpr int M      = 8192;             // bitonic size (pow2 >= N_PER)

// decoupled-lookback status flags
constexpr unsigned long long FLG_A = 1ull << 62;   // aggregate ready
constexpr unsigned long long FLG_I = 2ull << 62;   // inclusive ready

// bijective XCD-chunked block swizzle: grid must be a multiple of 8
__device__ __forceinline__ int swz8(int bid, int chunk) {
    return (bid & 7) * chunk + (bid >> 3);
}

// padded LDS index for u64 keys: +1 slot per 8 -> breaks 64B-stride bank aliasing
__device__ __forceinline__ int ph(int i) { return i + (i >> 3); }

// ---------------- in-degree count: per-graph-half LDS histogram, plain stores ----------------
__global__ __launch_bounds__(1024) void k_count(const int* __restrict__ col,
                                                int* __restrict__ cnt2) {
    __shared__ int h[N_PER];  // 20 KB
    int lb = swz8(blockIdx.x, 25);       // 0..199, XCD-contiguous graphs
    int g = lb >> 1, half = lb & 1;
    for (int i = threadIdx.x; i < N_PER; i += 1024) h[i] = 0;
    __syncthreads();
    int ebase = g * E_PER + half * (E_PER / 2);
    int nbase = g * N_PER;
    const int4* c4 = (const int4*)(col + ebase);    // 16B-aligned
    for (int i = threadIdx.x; i < E_PER / 2 / 4; i += 1024) {
        int4 v = c4[i];
        atomicAdd(&h[v.x - nbase], 1);
        atomicAdd(&h[v.y - nbase], 1);
        atomicAdd(&h[v.z - nbase], 1);
        atomicAdd(&h[v.w - nbase], 1);
    }
    __syncthreads();
    int* dst = cnt2 + half * N + nbase;
    for (int i = threadIdx.x; i < N_PER; i += 1024) dst[i] = h[i];
}

// ---------------- deg = halves sum; dis = (1+deg)^-0.5 (int4/float4 vectorized) ----------------
__global__ void k_dis(const int4* __restrict__ cnt2a, const int4* __restrict__ cnt2b,
                      int4* __restrict__ cnt, float4* __restrict__ dis) {
    int i = blockIdx.x * blockDim.x + threadIdx.x;
    if (i < N / 4) {
        int4 a = cnt2a[i], b = cnt2b[i];
        int4 c = make_int4(a.x + b.x, a.y + b.y, a.z + b.z, a.w + b.w);
        cnt[i] = c;
        float4 d;
        d.x = __fdiv_rn(1.0f, __fsqrt_rn((float)(1 + c.x)));
        d.y = __fdiv_rn(1.0f, __fsqrt_rn((float)(1 + c.y)));
        d.z = __fdiv_rn(1.0f, __fsqrt_rn((float)(1 + c.z)));
        d.w = __fdiv_rn(1.0f, __fsqrt_rn((float)(1 + c.w)));
        dis[i] = d;
    }
}

// ---------------- fused: adjacency-in-LDS + bit-exact score ----------------
// 8 blocks per graph; block owns a 625-node subrange; adjacency never touches HBM.
// Proven structure (R10/R13, 256 us): LDS-atomic append + per-thread insertion sort,
// 1024 threads, 2 blocks/CU. Structural rewrites regressed 4x (R6/R7/R11/R14) -- keep.
__global__ __launch_bounds__(1024) void k_score_fused(const int* __restrict__ row,
                                                      const int* __restrict__ col,
                                                      const int* __restrict__ cnt,
                                                      const float* __restrict__ dis,
                                                      const float* __restrict__ scW,
                                                      const float* __restrict__ scB,
                                                      float* __restrict__ score) {
    __shared__ float dis_l[N_PER];   // 20000 B
    __shared__ int   wsum[16];       //    64 B
    __shared__ int   offs_l[SUBR];   //  2500 B
    __shared__ int   curs_l[SUBR];   //  2500 B
    __shared__ int   list[LCAP];     // 46560 B   total ~71.6 KB -> 2 blocks/CU
    int lb = swz8(blockIdx.x, 100);  // 0..799, XCD-contiguous
    int g = lb >> 3, q = lb & 7;
    int t = threadIdx.x;
    int nbase = g * N_PER;
    int ebase = g * E_PER;
    int lo = q * SUBR;

    // P1: load precomputed dis for the whole graph into LDS (float4, L2-hot)
    const float4* d4 = (const float4*)(dis + nbase);   // 20000 B offset -> 16B aligned
    for (int j4 = t; j4 < N_PER / 4; j4 += 1024) {
        float4 dv4 = d4[j4];
        int j = 4 * j4;
        dis_l[j]     = dv4.x;
        dis_l[j + 1] = dv4.y;
        dis_l[j + 2] = dv4.z;
        dis_l[j + 3] = dv4.w;
    }

    // P2: wave-shuffle inclusive scan of own-subrange degrees (3 barriers total)
    int v = (t < SUBR) ? cnt[nbase + lo + t] : 0;
    int lane = t & 63, wid = t >> 6;
    int x = v;
#pragma unroll
    for (int s = 1; s < 64; s <<= 1) {
        int o = __shfl_up(x, s, 64);
        if (lane >= s) x += o;
    }
    if (lane == 63) wsum[wid] = x;
    __syncthreads();
    if (wid == 0) {
        int ws = (lane < 16) ? wsum[lane] : 0;
#pragma unroll
        for (int s = 1; s < 16; s <<= 1) {
            int o = __shfl_up(ws, s, 64);
            if (lane >= s) ws += o;
        }
        if (lane < 16) wsum[lane] = ws;
    }
    __syncthreads();
    int incl = x + (wid > 0 ? wsum[wid - 1] : 0);
    if (t < SUBR) { offs_l[t] = incl - v + t; curs_l[t] = 0; }  // +t bank skew
    __syncthreads();

    // P3: stream edges in epochs (int4 col AND row); append matches,
    // packed (e_local<<13)|row_local. Barrier per epoch orders appends across epochs.
    const int4* c4 = (const int4*)(col + ebase);    // 16B-aligned
    const int4* r4 = (const int4*)(row + ebase);
    for (int ep = 0; ep < NEPOCH; ep++) {
        for (int i4 = ep * EP_I4 + t; i4 < (ep + 1) * EP_I4; i4 += 1024) {
            int4 cv = c4[i4];
            int4 rv = r4[i4];
            int i0 = 4 * i4;
#pragma unroll
            for (int m = 0; m < 4; m++) {
                int cl = ((m == 0) ? cv.x : (m == 1) ? cv.y : (m == 2) ? cv.z : cv.w) - nbase;
                int rl = ((m == 0) ? rv.x : (m == 1) ? rv.y : (m == 2) ? rv.z : rv.w) - nbase;
                unsigned d = (unsigned)(cl - lo);
                if (d < (unsigned)SUBR) {
                    int i = i0 + m;
                    int slot = atomicAdd(&curs_l[d], 1);
                    int pos = offs_l[d] + slot;
                    if (pos < LCAP) list[pos] = (i << 13) | rl;
                }
            }
        }
        __syncthreads();
    }

    // P4: insertion sort ascending edge id (near-sorted input -> few shifts), bit-exact fold
    if (t < SUBR) {
        int base = offs_l[t];
        int k = v;
        if (base + k > LCAP) k = 0;          // overflow guard (probability ~0)
        for (int i = 1; i < k; i++) {
            int key = list[base + i];
            int j = i - 1;
            while (j >= 0 && list[base + j] > key) { list[base + j + 1] = list[base + j]; j--; }
            list[base + j + 1] = key;
        }
        float w = scW[0];
        float dv = dis_l[lo + t];
        float s = 0.0f;
        for (int i = 0; i < k; i++) {
            int rl = list[base + i] & 8191;
            s = __fadd_rn(s, __fmul_rn(w, __fmul_rn(dis_l[rl], dv)));
        }
        s = __fadd_rn(s, __fmul_rn(w, __fmul_rn(dv, dv)));  // self-loop term
        s = __fadd_rn(s, scB[0]);
        score[nbase + lo + t] = s;
    }
}

// ---------------- per-graph stable top-k: register-blocked bitonic sort ----------------
__global__ __launch_bounds__(1024) void k_topk(const float* __restrict__ score,
                                               float* __restrict__ out_batch,
                                               float* __restrict__ out_perm,
                                               int* __restrict__ perm_i,
                                               int* __restrict__ n_idx) {
    __shared__ unsigned long long keys[M + (M >> 3)];  // 9216 u64 = 73728 B (padded)
    int b = blockIdx.x, t = threadIdx.x;
    int base = 8 * t;

    unsigned long long v[8];
    if (t < 625) {   // 8*625 = 5000 = N_PER exactly
        const float4* s4 = (const float4*)(score + b * N_PER + base);
        float4 f0 = s4[0], f1 = s4[1];
        float fs[8] = {f0.x, f0.y, f0.z, f0.w, f1.x, f1.y, f1.z, f1.w};
#pragma unroll
        for (int m = 0; m < 8; m++) {
            unsigned u = __float_as_uint(fs[m]);
            unsigned asc = u ^ ((u & 0x80000000u) ? 0xFFFFFFFFu : 0x80000000u);
            v[m] = ((unsigned long long)(~asc) << 32) | (unsigned)(base + m);
        }
    } else {
#pragma unroll
        for (int m = 0; m < 8; m++) v[m] = ~0ull;  // padding sorts last
    }

#define CEV(x, y, up) { if ((v[x] > v[y]) == (up)) { unsigned long long tmp = v[x]; v[x] = v[y]; v[y] = tmp; } }
    CEV(0, 1, true)  CEV(2, 3, false) CEV(4, 5, true)  CEV(6, 7, false)      // k=2
    CEV(0, 2, true)  CEV(1, 3, true)  CEV(4, 6, false) CEV(5, 7, false)      // k=4 j=2
    CEV(0, 1, true)  CEV(2, 3, true)  CEV(4, 5, false) CEV(6, 7, false)      // k=4 j=1
    {
        bool u8 = ((t & 1) == 0);                                            // k=8
        CEV(0, 4, u8) CEV(1, 5, u8) CEV(2, 6, u8) CEV(3, 7, u8)
        CEV(0, 2, u8) CEV(1, 3, u8) CEV(4, 6, u8) CEV(5, 7, u8)
        CEV(0, 1, u8) CEV(2, 3, u8) CEV(4, 5, u8) CEV(6, 7, u8)
    }
#pragma unroll
    for (int m = 0; m < 8; m++) keys[ph(base + m)] = v[m];
    __syncthreads();

    for (int k = 16; k <= M; k <<= 1) {
        bool last = (k == M);
        for (int j = k >> 1; j >= 8; j >>= 1) {
            int np = (last && j < (M >> 1)) ? (M >> 2) : (M >> 1);
            for (int p = t; p < np; p += 1024) {
                int i = ((p & ~(j - 1)) << 1) | (p & (j - 1));
                int ip = i | j;
                bool up = ((i & k) == 0);
                unsigned long long a = keys[ph(i)];
                unsigned long long c = keys[ph(ip)];
                if ((a > c) == up) { keys[ph(i)] = c; keys[ph(ip)] = a; }
            }
            __syncthreads();
        }
        int nb = last ? 512 : 1024;   // last stage: register pass only on [0,4096)
        if (t < nb) {
            bool up = ((base & k) == 0);
            unsigned long long w[8];
#pragma unroll
            for (int m = 0; m < 8; m++) w[m] = keys[ph(base + m)];
#define CEW(x, y) { if ((w[x] > w[y]) == up) { unsigned long long tmp = w[x]; w[x] = w[y]; w[y] = tmp; } }
            CEW(0, 4) CEW(1, 5) CEW(2, 6) CEW(3, 7)   // j=4
            CEW(0, 2) CEW(1, 3) CEW(4, 6) CEW(5, 7)   // j=2
            CEW(0, 1) CEW(2, 3) CEW(4, 5) CEW(6, 7)   // j=1
#pragma unroll
            for (int m = 0; m < 8; m++) keys[ph(base + m)] = w[m];
        }
        __syncthreads();
    }

    for (int r = t; r < K_PER; r += 1024) {
        unsigned long long key = keys[ph(r)];
        int idx = (int)(key & 0xFFFFFFFFull);
        int gl = b * N_PER + idx;
        int ni = b * K_PER + r;
        perm_i[ni] = gl;
        n_idx[gl] = ni;
        out_perm[ni] = (float)gl;
        out_batch[ni] = (float)b;
    }
}

// ---------------- x_new = x[perm] * tanh(score[perm]) ----------------
__global__ void k_xnew(const float4* __restrict__ x4, const float* __restrict__ score,
                       const int* __restrict__ perm_i, float4* __restrict__ out4) {
    int tid = blockIdx.x * blockDim.x + threadIdx.x;
    if (tid >= NK * (D_HID / 4)) return;
    int i = tid >> 5;       // row (D_HID/4 = 32 float4 per row)
    int c = tid & 31;
    int g = perm_i[i];
    float ts = tanhf(score[g]);
    float4 v = x4[(long)g * 32 + c];
    v.x *= ts; v.y *= ts; v.z *= ts; v.w *= ts;
    out4[tid] = v;
}

// ---------------- prefill: edge outputs = -1, n_idx = -1, status = 0 (no deps) ----------------
__global__ void k_prefill(float4* __restrict__ oe0, float4* __restrict__ oe1,
                          int4* __restrict__ n_idx4,
                          unsigned long long* __restrict__ status) {
    int i = blockIdx.x * blockDim.x + threadIdx.x;
    int stride = gridDim.x * blockDim.x;
    float4 m1 = make_float4(-1.0f, -1.0f, -1.0f, -1.0f);
    for (int j = i; j < E / 4; j += stride) { oe0[j] = m1; oe1[j] = m1; }
    int4 mi = make_int4(-1, -1, -1, -1);
    for (int j = i; j < N / 4; j += stride) n_idx4[j] = mi;
    for (int j = i; j < NBLK_E; j += stride) status[j] = 0ull;
}

// ---------------- single-pass order-preserving edge compaction (decoupled lookback) ----------------
__global__ __launch_bounds__(256) void k_compact(const int* __restrict__ row,
                                                 const int* __restrict__ col,
                                                 const int* __restrict__ n_idx,
                                                 unsigned long long* __restrict__ status,
                                                 float* __restrict__ oe0,
                                                 float* __restrict__ oe1) {
    __shared__ int wsum[4];
    __shared__ int excl_sh;
    int blk = blockIdx.x, t = threadIdx.x;
    int base = blk * EPB + t * EPT;
    int rr[EPT], cc[EPT];
    int cnt = 0;
    if (blk < NBLK_E - 1) {
        // full block: int4 fast path (base is 16-int aligned)
#pragma unroll
        for (int i4 = 0; i4 < 4; i4++) {
            int4 rv = ((const int4*)(row + base))[i4];
            int4 cv = ((const int4*)(col + base))[i4];
            rr[4 * i4 + 0] = n_idx[rv.x];  cc[4 * i4 + 0] = n_idx[cv.x];
            rr[4 * i4 + 1] = n_idx[rv.y];  cc[4 * i4 + 1] = n_idx[cv.y];
            rr[4 * i4 + 2] = n_idx[rv.z];  cc[4 * i4 + 2] = n_idx[cv.z];
            rr[4 * i4 + 3] = n_idx[rv.w];  cc[4 * i4 + 3] = n_idx[cv.w];
        }
#pragma unroll
        for (int i = 0; i < EPT; i++)
            if (rr[i] >= 0 && cc[i] >= 0) cnt++;
    } else {
        // ragged last block: scalar guarded path
#pragma unroll
        for (int i = 0; i < EPT; i++) {
            int e = base + i;
            int rv = -1, cv = -1;
            if (e < E) { rv = n_idx[row[e]]; cv = n_idx[col[e]]; }
            rr[i] = rv; cc[i] = cv;
            if (rv >= 0 && cv >= 0) cnt++;
        }
    }
    // wave-shuffle inclusive scan over 256 threads (4 waves, 2 barriers)
    int lane = t & 63, wid = t >> 6;
    int x = cnt;
#pragma unroll
    for (int s = 1; s < 64; s <<= 1) {
        int o = __shfl_up(x, s, 64);
        if (lane >= s) x += o;
    }
    if (lane == 63) wsum[wid] = x;
    __syncthreads();
    if (t == 0) {
        int a0 = wsum[0], a1 = wsum[1], a2 = wsum[2];
        wsum[1] = a0; wsum[2] = a0 + a1; wsum[3] = a0 + a1 + a2;
        wsum[0] = 0;
    }
    __syncthreads();
    int incl = x + wsum[wid];
    int agg;
    {
        __shared__ int agg_sh;
        if (t == 255) agg_sh = incl;   // thread 255 holds block-inclusive total
        __syncthreads();
        agg = agg_sh;
    }
    if (t == 0) {
        if (blk == 0) {
            atomicExch(&status[0], FLG_I | (unsigned long long)(unsigned)agg);
            excl_sh = 0;
        } else {
            atomicExch(&status[blk], FLG_A | (unsigned long long)(unsigned)agg);
            unsigned long long ex = 0;
            for (int i = blk - 1; i >= 0; i--) {
                unsigned long long sv;
                do { sv = atomicAdd(&status[i], 0ull); } while (sv == 0ull);
                ex += (sv & 0xFFFFFFFFull);
                if (sv & FLG_I) break;
            }
            atomicExch(&status[blk], FLG_I | (ex + (unsigned long long)(unsigned)agg));
            excl_sh = (int)ex;
        }
    }
    __syncthreads();
    int pos = excl_sh + incl - cnt;
#pragma unroll
    for (int i = 0; i < EPT; i++) {
        if (rr[i] >= 0 && cc[i] >= 0) {
            oe0[pos] = (float)rr[i];
            oe1[pos] = (float)cc[i];
            pos++;
        }
    }
}

extern "C" void kernel_launch(void* const* d_in, const int* in_sizes, int n_in,
                              void* d_out, int out_size, void* d_ws, size_t ws_size,
                              hipStream_t stream) {
    const float* x   = (const float*)d_in[0];
    const float* scW = (const float*)d_in[4];
    const float* scB = (const float*)d_in[5];
    const int*   edge = (const int*)d_in[6];
    const int*   row = edge;
    const int*   col = edge + E;

    // workspace layout: status (u64, 8B-aligned at base) then ints/floats
    unsigned long long* status = (unsigned long long*)d_ws;   // NBLK_E
    int*   ws_i    = (int*)(status + NBLK_E);
    int*   cnt2    = ws_i;                   // 2N (half histograms)
    int*   deg_cnt = ws_i + 2 * N;           // N  (summed)
    float* dis     = (float*)(ws_i + 3 * N); // N
    float* score   = (float*)(ws_i + 4 * N); // N
    int*   n_idx   = ws_i + 5 * N;           // N
    int*   perm_i  = ws_i + 6 * N;           // NK

    // output layout: x_new [NK, D_HID] | edge_new [2, E] | batch_new [NK] | perm [NK]
    float* out_x     = (float*)d_out;
    float* oe0       = out_x + (size_t)NK * D_HID;
    float* oe1       = oe0 + E;
    float* out_batch = oe1 + E;
    float* out_perm  = out_batch + NK;

    k_prefill<<<2048, 256, 0, stream>>>((float4*)oe0, (float4*)oe1, (int4*)n_idx, status);
    k_count<<<200, 1024, 0, stream>>>(col, cnt2);
    k_dis<<<(N / 4 + 255) / 256, 256, 0, stream>>>((const int4*)cnt2, (const int4*)(cnt2 + N),
                                                   (int4*)deg_cnt, (float4*)dis);
    k_score_fused<<<800, 1024, 0, stream>>>(row, col, deg_cnt, dis, scW, scB, score);
    k_topk<<<B, 1024, 0, stream>>>(score, out_batch, out_perm, perm_i, n_idx);
    k_xnew<<<(NK * (D_HID / 4) + 255) / 256, 256, 0, stream>>>((const float4*)x, score, perm_i,
                                                               (float4*)out_x);
    k_compact<<<NBLK_E, 256, 0, stream>>>(row, col, n_idx, status, oe0, oe1);
}